// Round 2
// baseline (1275.793 us; speedup 1.0000x reference)
//
#include <hip/hip_runtime.h>
#include <math.h>

// Problem constants
#define BATCH 8192
#define HID   1024
#define FH    96
#define OO    8
#define EE    36
#define NLV   (FH*EE)   // 3456
#define NM    (FH*OO)   // 768

typedef short bf16x8 __attribute__((ext_vector_type(8)));
typedef float f32x4  __attribute__((ext_vector_type(4)));

// d_out layout (floats): means | precision | D | T   (reference return order)
static const size_t OFF_P = (size_t)BATCH * FH * OO;
static const size_t OFF_D = OFF_P + (size_t)BATCH * FH * 64;
static const size_t OFF_T = OFF_D + (size_t)BATCH * FH * 64;

// bf16 helpers via raw bits (avoids hip_bf16 API drift). RNE rounding.
__device__ __forceinline__ unsigned short f2bf(float f) {
    unsigned int u = __float_as_uint(f);
    u += 0x7fffu + ((u >> 16) & 1u);
    return (unsigned short)(u >> 16);
}
__device__ __forceinline__ float bf2f(unsigned short s) {
    return __uint_as_float(((unsigned int)s) << 16);
}

// ---------------------------------------------------------------------------
// Repack W (fp32 [K=1024][N]) -> Wt_hi/Wt_lo (bf16-as-ushort [N][1024]),
// split so that W ≈ hi + lo with |lo| <= 2^-9 |W|, residual <= 2^-18 |W|.
// LDS-tiled 32x32 transpose: coalesced reads AND writes.
__global__ __launch_bounds__(256) void transpose_split(const float* __restrict__ W,
                                                       unsigned short* __restrict__ Th,
                                                       unsigned short* __restrict__ Tl,
                                                       int N)
{
    __shared__ float sh[32][33];
    const int tx = threadIdx.x;          // 0..31
    const int ty = threadIdx.y;          // 0..7
    const int n0 = blockIdx.x * 32;
    const int k0 = blockIdx.y * 32;
#pragma unroll
    for (int i = 0; i < 4; ++i) {
        int kl = ty + i * 8;
        sh[kl][tx] = W[(size_t)(k0 + kl) * N + n0 + tx];
    }
    __syncthreads();
#pragma unroll
    for (int i = 0; i < 4; ++i) {
        int nl = ty + i * 8;
        float v = sh[tx][nl];
        unsigned short h = f2bf(v);
        unsigned short l = f2bf(v - bf2f(h));
        size_t o = (size_t)(n0 + nl) * HID + k0 + tx;
        Th[o] = h;
        Tl[o] = l;
    }
}

// ---------------------------------------------------------------------------
// Split-bf16 MFMA GEMM: C[M x N] = A[M x 1024] @ W[1024 x N] + bias (opt silu)
// A fp32 (split to hi/lo on stage); W pre-split bf16 [N][K] row-major.
// 3 MFMA passes: Ah*Wh + Ah*Wl + Al*Wh  (Al*Wl dropped, ~2^-18 relative).
// Tile 128x128, BK=32, 256 threads = 4 waves in 2x2; per wave 4x4 frags of
// v_mfma_f32_16x16x32_bf16.
//   A frag: row = lane&15, k = 8*(lane>>4)+e   (guide §3, m89-verified family)
//   B frag: col = lane&15, k = 8*(lane>>4)+e
//   D frag: col = lane&15, row = 4*(lane>>4)+reg
template<int ACT>
__global__ __launch_bounds__(256) void gemm_split(const float* __restrict__ A,
                                                  const unsigned short* __restrict__ Bh,
                                                  const unsigned short* __restrict__ Bl,
                                                  const float* __restrict__ bias,
                                                  float* __restrict__ C,
                                                  int N)
{
    __shared__ unsigned short AhL[128 * 32];
    __shared__ unsigned short AlL[128 * 32];
    __shared__ unsigned short BhL[128 * 32];
    __shared__ unsigned short BlL[128 * 32];

    const int tid  = threadIdx.x;
    const int lane = tid & 63;
    const int wave = tid >> 6;
    const int wm0  = (wave >> 1) * 64;
    const int wn0  = (wave & 1) * 64;
    const int m0   = blockIdx.x * 128;
    const int n0   = blockIdx.y * 128;
    const int l15  = lane & 15;
    const int l4   = lane >> 4;

    f32x4 acc[4][4];
#pragma unroll
    for (int i = 0; i < 4; ++i)
#pragma unroll
        for (int j = 0; j < 4; ++j)
            acc[i][j] = (f32x4){0.f, 0.f, 0.f, 0.f};

    for (int k0 = 0; k0 < HID; k0 += 32) {
        __syncthreads();
        // ---- stage A tile 128x32 fp32 -> hi/lo bf16 in LDS ----
#pragma unroll
        for (int p = 0; p < 4; ++p) {
            int idx = p * 256 + tid;             // 0..1023
            int ra  = idx >> 3;                  // 0..127
            int c4  = idx & 7;                   // 0..7 (float4 index)
            float4 v = *reinterpret_cast<const float4*>(
                A + (size_t)(m0 + ra) * HID + k0 + c4 * 4);
            unsigned short h0 = f2bf(v.x), h1 = f2bf(v.y),
                           h2 = f2bf(v.z), h3 = f2bf(v.w);
            short4 hv = make_short4((short)h0, (short)h1, (short)h2, (short)h3);
            short4 lw = make_short4((short)f2bf(v.x - bf2f(h0)),
                                    (short)f2bf(v.y - bf2f(h1)),
                                    (short)f2bf(v.z - bf2f(h2)),
                                    (short)f2bf(v.w - bf2f(h3)));
            *reinterpret_cast<short4*>(&AhL[ra * 32 + c4 * 4]) = hv;
            *reinterpret_cast<short4*>(&AlL[ra * 32 + c4 * 4]) = lw;
        }
        // ---- stage B tile 128x32 bf16 hi/lo (linear rows of Wt) ----
#pragma unroll
        for (int p = 0; p < 2; ++p) {
            int idx = p * 256 + tid;             // 0..511
            int rb  = idx >> 2;                  // 0..127
            int c8  = idx & 3;                   // 8-elem group
            size_t go = (size_t)(n0 + rb) * HID + k0 + c8 * 8;
            *reinterpret_cast<uint4*>(&BhL[rb * 32 + c8 * 8]) =
                *reinterpret_cast<const uint4*>(Bh + go);
            *reinterpret_cast<uint4*>(&BlL[rb * 32 + c8 * 8]) =
                *reinterpret_cast<const uint4*>(Bl + go);
        }
        __syncthreads();

        // ---- fragments + 48 MFMA ----
        bf16x8 ah[4], al[4];
#pragma unroll
        for (int mf = 0; mf < 4; ++mf) {
            int off = (wm0 + mf * 16 + l15) * 32 + l4 * 8;
            ah[mf] = *reinterpret_cast<const bf16x8*>(&AhL[off]);
            al[mf] = *reinterpret_cast<const bf16x8*>(&AlL[off]);
        }
#pragma unroll
        for (int nf = 0; nf < 4; ++nf) {
            int off = (wn0 + nf * 16 + l15) * 32 + l4 * 8;
            bf16x8 bh = *reinterpret_cast<const bf16x8*>(&BhL[off]);
            bf16x8 bl = *reinterpret_cast<const bf16x8*>(&BlL[off]);
#pragma unroll
            for (int mf = 0; mf < 4; ++mf) {
                acc[mf][nf] = __builtin_amdgcn_mfma_f32_16x16x32_bf16(ah[mf], bh, acc[mf][nf], 0, 0, 0);
                acc[mf][nf] = __builtin_amdgcn_mfma_f32_16x16x32_bf16(ah[mf], bl, acc[mf][nf], 0, 0, 0);
                acc[mf][nf] = __builtin_amdgcn_mfma_f32_16x16x32_bf16(al[mf], bh, acc[mf][nf], 0, 0, 0);
            }
        }
    }

    // ---- epilogue: bias (+silu), scattered-but-64B-coalesced stores ----
#pragma unroll
    for (int nf = 0; nf < 4; ++nf) {
        int gc = n0 + wn0 + nf * 16 + l15;
        float bb = bias[gc];
#pragma unroll
        for (int mf = 0; mf < 4; ++mf) {
#pragma unroll
            for (int r = 0; r < 4; ++r) {
                int gr = m0 + wm0 + mf * 16 + l4 * 4 + r;
                float o = acc[mf][nf][r] + bb;
                if (ACT) o = o / (1.f + __expf(-o));
                C[(size_t)gr * N + gc] = o;
            }
        }
    }
}

// ---------------------------------------------------------------------------
// MCD epilogue: per (row, head) group read 36 log-var values, emit
// precision (T^T D^-1 T), D, T. 1 thread = 1 group; fully thread-local.
__global__ __launch_bounds__(256) void mcd_epilogue(const float* __restrict__ lv,
                                                    float* __restrict__ out)
{
    const int gid  = blockIdx.x * 256 + threadIdx.x;   // 0..786431
    const int row  = gid / FH;
    const int head = gid - row * FH;

    const float* src = lv + (size_t)row * NLV + head * EE;
    float e[EE];
#pragma unroll
    for (int i = 0; i < 9; ++i)
        *reinterpret_cast<float4*>(&e[i * 4]) =
            reinterpret_cast<const float4*>(src)[i];

    float dv[OO], invd[OO];
#pragma unroll
    for (int i = 0; i < OO; ++i) {
        dv[i]   = __expf(0.5f * e[i]);
        invd[i] = 1.f / dv[i];
    }

    // T unit-upper; strictly-upper entries in np.triu_indices(8,1) order
    float Tu[OO][OO];
#pragma unroll
    for (int j = 0; j < OO; ++j) {
#pragma unroll
        for (int i = j + 1; i < OO; ++i) {
            Tu[j][i] = e[OO + j * 7 - (j * (j - 1)) / 2 + (i - j - 1)];
        }
    }

    float* Pp = out + OFF_P + (size_t)gid * 64;
    float* Dp = out + OFF_D + (size_t)gid * 64;
    float* Tp = out + OFF_T + (size_t)gid * 64;

    // precision[i][k] = sum_{j<=min(i,k)} T[j][i] * (T[j][k] * invd[j])
#pragma unroll
    for (int i = 0; i < OO; ++i) {
        float rowv[OO];
#pragma unroll
        for (int k = 0; k < OO; ++k) {
            float s = 0.f;
#pragma unroll
            for (int j = 0; j < OO; ++j) {
                if (j <= i && j <= k) {
                    float tji = (j == i) ? 1.f : Tu[j][i];
                    float tjk = (j == k) ? 1.f : Tu[j][k];
                    s = fmaf(tji, tjk * invd[j], s);
                }
            }
            rowv[k] = s;
        }
        *reinterpret_cast<float4*>(Pp + i * 8)     = make_float4(rowv[0], rowv[1], rowv[2], rowv[3]);
        *reinterpret_cast<float4*>(Pp + i * 8 + 4) = make_float4(rowv[4], rowv[5], rowv[6], rowv[7]);
    }

#pragma unroll
    for (int i = 0; i < OO; ++i) {
        float rowv[OO];
#pragma unroll
        for (int k = 0; k < OO; ++k) rowv[k] = (k == i) ? dv[i] : 0.f;
        *reinterpret_cast<float4*>(Dp + i * 8)     = make_float4(rowv[0], rowv[1], rowv[2], rowv[3]);
        *reinterpret_cast<float4*>(Dp + i * 8 + 4) = make_float4(rowv[4], rowv[5], rowv[6], rowv[7]);
    }

#pragma unroll
    for (int j = 0; j < OO; ++j) {
        float rowv[OO];
#pragma unroll
        for (int k = 0; k < OO; ++k)
            rowv[k] = (k < j) ? 0.f : (k == j) ? 1.f : Tu[j][k];
        *reinterpret_cast<float4*>(Tp + j * 8)     = make_float4(rowv[0], rowv[1], rowv[2], rowv[3]);
        *reinterpret_cast<float4*>(Tp + j * 8 + 4) = make_float4(rowv[4], rowv[5], rowv[6], rowv[7]);
    }
}

// ---------------------------------------------------------------------------
extern "C" void kernel_launch(void* const* d_in, const int* in_sizes, int n_in,
                              void* d_out, int out_size, void* d_ws, size_t ws_size,
                              hipStream_t stream)
{
    (void)in_sizes; (void)n_in; (void)out_size; (void)ws_size;
    const float* z  = (const float*)d_in[0];
    const float* W1 = (const float*)d_in[1];
    const float* b1 = (const float*)d_in[2];
    const float* W2 = (const float*)d_in[3];
    const float* b2 = (const float*)d_in[4];
    const float* Wm = (const float*)d_in[5];
    const float* bm = (const float*)d_in[6];
    const float* Wv = (const float*)d_in[7];
    const float* bv = (const float*)d_in[8];
    float* out = (float*)d_out;

    // ws layout (fp32 region then bf16/ushort region), ~205 MB total
    float* h1 = (float*)d_ws;                             //  8192*1024 f32
    float* h  = h1 + (size_t)BATCH * HID;                 //  8192*1024 f32
    float* lv = h  + (size_t)BATCH * HID;                 //  8192*3456 f32
    unsigned short* us = (unsigned short*)(lv + (size_t)BATCH * NLV);
    unsigned short* W1h = us;                 us += (size_t)HID * HID;
    unsigned short* W1l = us;                 us += (size_t)HID * HID;
    unsigned short* W2h = us;                 us += (size_t)HID * HID;
    unsigned short* W2l = us;                 us += (size_t)HID * HID;
    unsigned short* Wmh = us;                 us += (size_t)NM * HID;
    unsigned short* Wml = us;                 us += (size_t)NM * HID;
    unsigned short* Wvh = us;                 us += (size_t)NLV * HID;
    unsigned short* Wvl = us;

    dim3 tb(32, 8);
    transpose_split<<<dim3(HID / 32, HID / 32), tb, 0, stream>>>(W1, W1h, W1l, HID);
    transpose_split<<<dim3(HID / 32, HID / 32), tb, 0, stream>>>(W2, W2h, W2l, HID);
    transpose_split<<<dim3(NM  / 32, HID / 32), tb, 0, stream>>>(Wm, Wmh, Wml, NM);
    transpose_split<<<dim3(NLV / 32, HID / 32), tb, 0, stream>>>(Wv, Wvh, Wvl, NLV);

    // h1 = silu(z @ W1 + b1)
    gemm_split<1><<<dim3(BATCH / 128, HID / 128), 256, 0, stream>>>(z,  W1h, W1l, b1, h1, HID);
    // h = h1 @ W2 + b2
    gemm_split<0><<<dim3(BATCH / 128, HID / 128), 256, 0, stream>>>(h1, W2h, W2l, b2, h,  HID);
    // means = h @ Wm + bm   (directly into d_out)
    gemm_split<0><<<dim3(BATCH / 128, NM  / 128), 256, 0, stream>>>(h,  Wmh, Wml, bm, out, NM);
    // lv = h @ Wv + bv
    gemm_split<0><<<dim3(BATCH / 128, NLV / 128), 256, 0, stream>>>(h,  Wvh, Wvl, bv, lv, NLV);

    // precision / D / T
    mcd_epilogue<<<dim3(BATCH * FH / 256), 256, 0, stream>>>(lv, out);
}

// Round 3
// 1184.444 us; speedup vs baseline: 1.0771x; 1.0771x over previous
//
#include <hip/hip_runtime.h>
#include <math.h>

#define BATCH 8192
#define HID   1024
#define FH    96
#define OO    8
#define EE    36
#define NLV   (FH*EE)   // 3456
#define NM    (FH*OO)   // 768

typedef short  bf16x8 __attribute__((ext_vector_type(8)));
typedef float  f32x4  __attribute__((ext_vector_type(4)));
typedef unsigned short u16x8 __attribute__((ext_vector_type(8)));

// d_out layout (floats): means | precision | D | T
static const size_t OFF_P = (size_t)BATCH * FH * OO;
static const size_t OFF_D = OFF_P + (size_t)BATCH * FH * 64;
static const size_t OFF_T = OFF_D + (size_t)BATCH * FH * 64;

__device__ __forceinline__ unsigned short f2bf(float f) {
    unsigned int u = __float_as_uint(f);
    u += 0x7fffu + ((u >> 16) & 1u);
    return (unsigned short)(u >> 16);
}
__device__ __forceinline__ float bf2f(unsigned short s) {
    return __uint_as_float(((unsigned int)s) << 16);
}

// Block layout for GEMM operands (both A and B sides), K = HID always:
// elem (r, k) -> [r>>7][k>>3][r&127][k&7]; 128-row block stride = 128*HID.
// Property: a 128x32 tile at (rblk, k0) is 4 contiguous KB-sized kgrp slabs,
// so global_load_lds staging is linear AND fully coalesced.
__device__ __forceinline__ size_t blk_off(int r, int k) {
    return ((size_t)(r >> 7)) * (128 * HID) + (size_t)(k >> 3) * 1024
         + (size_t)(r & 127) * 8 + (size_t)(k & 7);
}

// async global->LDS, 16B per lane; LDS dest = wave-uniform base + lane*16
__device__ __forceinline__ void glds16(const unsigned short* g, unsigned short* l) {
    __builtin_amdgcn_global_load_lds(
        (const __attribute__((address_space(1))) unsigned int*)g,
        (__attribute__((address_space(3))) unsigned int*)l, 16, 0, 0);
}

// ---------------------------------------------------------------------------
// fp32 [R][HID] row-major -> hi/lo bf16 block layout. Contiguous writes.
__global__ __launch_bounds__(256) void conv_blockify(const float* __restrict__ X,
                                                     unsigned short* __restrict__ Xh,
                                                     unsigned short* __restrict__ Xl)
{
    int idx  = blockIdx.x * 256 + threadIdx.x;   // one 8-elem chunk
    int row  = idx & 127;
    int kgrp = (idx >> 7) & 127;
    int rblk = idx >> 14;
    const float* src = X + ((size_t)(rblk * 128 + row)) * HID + kgrp * 8;
    float4 v0 = reinterpret_cast<const float4*>(src)[0];
    float4 v1 = reinterpret_cast<const float4*>(src)[1];
    float vv[8] = {v0.x, v0.y, v0.z, v0.w, v1.x, v1.y, v1.z, v1.w};
    u16x8 h, l;
#pragma unroll
    for (int j = 0; j < 8; ++j) {
        unsigned short hh = f2bf(vv[j]);
        h[j] = hh;
        l[j] = f2bf(vv[j] - bf2f(hh));
    }
    *reinterpret_cast<u16x8*>(Xh + (size_t)idx * 8) = h;
    *reinterpret_cast<u16x8*>(Xl + (size_t)idx * 8) = l;
}

// ---------------------------------------------------------------------------
// W (fp32 [K=HID][N]) -> hi/lo bf16, transposed into block layout (r = n).
__global__ __launch_bounds__(256) void transpose_split_blk(const float* __restrict__ W,
                                                           unsigned short* __restrict__ Th,
                                                           unsigned short* __restrict__ Tl,
                                                           int N)
{
    __shared__ float sh[32][33];
    const int tx = threadIdx.x;          // 0..31
    const int ty = threadIdx.y;          // 0..7
    const int n0 = blockIdx.x * 32;
    const int k0 = blockIdx.y * 32;
#pragma unroll
    for (int i = 0; i < 4; ++i) {
        int kl = ty + i * 8;
        sh[kl][tx] = W[(size_t)(k0 + kl) * N + n0 + tx];
    }
    __syncthreads();
#pragma unroll
    for (int i = 0; i < 4; ++i) {
        int nl = ty + i * 8;
        float v = sh[tx][nl];            // = W[k0+tx][n0+nl]
        unsigned short h = f2bf(v);
        unsigned short l = f2bf(v - bf2f(h));
        size_t o = blk_off(n0 + nl, k0 + tx);
        Th[o] = h;
        Tl[o] = l;
    }
}

// ---------------------------------------------------------------------------
// Split-bf16 MFMA GEMM, both operands pre-split hi/lo in block layout.
// C = A @ B^T(+bias): 3 passes AhBh + AhBl + AlBh. Tile 128x128, BK=32,
// 4 waves 2x2, per-wave 4x4 frags of v_mfma_f32_16x16x32_bf16.
// Staging: global_load_lds 16B/lane, linear (block layout makes it coalesced).
// OUTBLK=0: fp32 row-major out (+bias, opt silu). OUTBLK=1: hi/lo block out.
template<int ACT, int OUTBLK>
__global__ __launch_bounds__(256) void gemm_bs(
    const unsigned short* __restrict__ Ah_, const unsigned short* __restrict__ Al_,
    const unsigned short* __restrict__ Bh_, const unsigned short* __restrict__ Bl_,
    const float* __restrict__ bias,
    float* __restrict__ Cf,
    unsigned short* __restrict__ Ch, unsigned short* __restrict__ Cl,
    int N)
{
    __shared__ unsigned short AhL[4096];   // [4 kgrp][128 row][8] = 8 KB
    __shared__ unsigned short AlL[4096];
    __shared__ unsigned short BhL[4096];
    __shared__ unsigned short BlL[4096];

    const int tid  = threadIdx.x;
    const int lane = tid & 63;
    const int wave = tid >> 6;
    const int m0   = blockIdx.x * 128;
    const int n0   = blockIdx.y * 128;
    const int wm0  = (wave >> 1) * 64;
    const int wn0  = (wave & 1) * 64;
    const int l15  = lane & 15;
    const int l4   = lane >> 4;

    const unsigned short* Ah = Ah_ + (size_t)(m0 >> 7) * (128 * HID);
    const unsigned short* Al = Al_ + (size_t)(m0 >> 7) * (128 * HID);
    const unsigned short* Bh = Bh_ + (size_t)(n0 >> 7) * (128 * HID);
    const unsigned short* Bl = Bl_ + (size_t)(n0 >> 7) * (128 * HID);

    f32x4 acc[4][4];
#pragma unroll
    for (int i = 0; i < 4; ++i)
#pragma unroll
        for (int j = 0; j < 4; ++j)
            acc[i][j] = (f32x4){0.f, 0.f, 0.f, 0.f};

    const int c0 = wave * 2;       // each wave stages chunks {c0, c0+1} of each buffer
    const int c1 = c0 + 1;

    for (int k0 = 0; k0 < HID; k0 += 32) {
        __syncthreads();           // prev iter's frag reads done before overwrite
        const size_t tb = (size_t)(k0 >> 3) * 1024;   // tile base (elems) in block layout
        const size_t o0 = tb + (size_t)c0 * 512 + (size_t)lane * 8;
        const size_t o1 = tb + (size_t)c1 * 512 + (size_t)lane * 8;
        glds16(Ah + o0, AhL + c0 * 512);
        glds16(Ah + o1, AhL + c1 * 512);
        glds16(Al + o0, AlL + c0 * 512);
        glds16(Al + o1, AlL + c1 * 512);
        glds16(Bh + o0, BhL + c0 * 512);
        glds16(Bh + o1, BhL + c1 * 512);
        glds16(Bl + o0, BlL + c0 * 512);
        glds16(Bl + o1, BlL + c1 * 512);
        __syncthreads();           // compiler inserts vmcnt(0) drain here

        bf16x8 a_h[4], a_l[4];
#pragma unroll
        for (int mf = 0; mf < 4; ++mf) {
            int off = l4 * 1024 + (wm0 + mf * 16 + l15) * 8;
            a_h[mf] = *reinterpret_cast<const bf16x8*>(&AhL[off]);
            a_l[mf] = *reinterpret_cast<const bf16x8*>(&AlL[off]);
        }
#pragma unroll
        for (int nf = 0; nf < 4; ++nf) {
            int off = l4 * 1024 + (wn0 + nf * 16 + l15) * 8;
            bf16x8 b_h = *reinterpret_cast<const bf16x8*>(&BhL[off]);
            bf16x8 b_l = *reinterpret_cast<const bf16x8*>(&BlL[off]);
#pragma unroll
            for (int mf = 0; mf < 4; ++mf) {
                acc[mf][nf] = __builtin_amdgcn_mfma_f32_16x16x32_bf16(a_h[mf], b_h, acc[mf][nf], 0, 0, 0);
                acc[mf][nf] = __builtin_amdgcn_mfma_f32_16x16x32_bf16(a_h[mf], b_l, acc[mf][nf], 0, 0, 0);
                acc[mf][nf] = __builtin_amdgcn_mfma_f32_16x16x32_bf16(a_l[mf], b_h, acc[mf][nf], 0, 0, 0);
            }
        }
    }

    // ---- epilogue ----
#pragma unroll
    for (int nf = 0; nf < 4; ++nf) {
        int gc = n0 + wn0 + nf * 16 + l15;
        float bb = bias[gc];
#pragma unroll
        for (int mf = 0; mf < 4; ++mf) {
#pragma unroll
            for (int r = 0; r < 4; ++r) {
                int gr = m0 + wm0 + mf * 16 + l4 * 4 + r;
                float o = acc[mf][nf][r] + bb;
                if (ACT) o = o / (1.f + __expf(-o));
                if (OUTBLK == 0) {
                    Cf[(size_t)gr * N + gc] = o;
                } else {
                    unsigned short h = f2bf(o);
                    unsigned short l = f2bf(o - bf2f(h));
                    size_t off = blk_off(gr, gc);   // N == HID for these stages
                    Ch[off] = h;
                    Cl[off] = l;
                }
            }
        }
    }
}

// ---------------------------------------------------------------------------
// MCD epilogue: per (row, head) group read 36 log-var values, emit
// precision (T^T D^-1 T), D, T. 1 thread = 1 group; fully thread-local.
__global__ __launch_bounds__(256) void mcd_epilogue(const float* __restrict__ lv,
                                                    float* __restrict__ out)
{
    const int gid  = blockIdx.x * 256 + threadIdx.x;
    const int row  = gid / FH;
    const int head = gid - row * FH;

    const float* src = lv + (size_t)row * NLV + head * EE;
    float e[EE];
#pragma unroll
    for (int i = 0; i < 9; ++i)
        *reinterpret_cast<float4*>(&e[i * 4]) =
            reinterpret_cast<const float4*>(src)[i];

    float dv[OO], invd[OO];
#pragma unroll
    for (int i = 0; i < OO; ++i) {
        dv[i]   = __expf(0.5f * e[i]);
        invd[i] = 1.f / dv[i];
    }

    float Tu[OO][OO];
#pragma unroll
    for (int j = 0; j < OO; ++j) {
#pragma unroll
        for (int i = j + 1; i < OO; ++i) {
            Tu[j][i] = e[OO + j * 7 - (j * (j - 1)) / 2 + (i - j - 1)];
        }
    }

    float* Pp = out + OFF_P + (size_t)gid * 64;
    float* Dp = out + OFF_D + (size_t)gid * 64;
    float* Tp = out + OFF_T + (size_t)gid * 64;

#pragma unroll
    for (int i = 0; i < OO; ++i) {
        float rowv[OO];
#pragma unroll
        for (int k = 0; k < OO; ++k) {
            float s = 0.f;
#pragma unroll
            for (int j = 0; j < OO; ++j) {
                if (j <= i && j <= k) {
                    float tji = (j == i) ? 1.f : Tu[j][i];
                    float tjk = (j == k) ? 1.f : Tu[j][k];
                    s = fmaf(tji, tjk * invd[j], s);
                }
            }
            rowv[k] = s;
        }
        *reinterpret_cast<float4*>(Pp + i * 8)     = make_float4(rowv[0], rowv[1], rowv[2], rowv[3]);
        *reinterpret_cast<float4*>(Pp + i * 8 + 4) = make_float4(rowv[4], rowv[5], rowv[6], rowv[7]);
    }

#pragma unroll
    for (int i = 0; i < OO; ++i) {
        float rowv[OO];
#pragma unroll
        for (int k = 0; k < OO; ++k) rowv[k] = (k == i) ? dv[i] : 0.f;
        *reinterpret_cast<float4*>(Dp + i * 8)     = make_float4(rowv[0], rowv[1], rowv[2], rowv[3]);
        *reinterpret_cast<float4*>(Dp + i * 8 + 4) = make_float4(rowv[4], rowv[5], rowv[6], rowv[7]);
    }

#pragma unroll
    for (int j = 0; j < OO; ++j) {
        float rowv[OO];
#pragma unroll
        for (int k = 0; k < OO; ++k)
            rowv[k] = (k < j) ? 0.f : (k == j) ? 1.f : Tu[j][k];
        *reinterpret_cast<float4*>(Tp + j * 8)     = make_float4(rowv[0], rowv[1], rowv[2], rowv[3]);
        *reinterpret_cast<float4*>(Tp + j * 8 + 4) = make_float4(rowv[4], rowv[5], rowv[6], rowv[7]);
    }
}

// ---------------------------------------------------------------------------
extern "C" void kernel_launch(void* const* d_in, const int* in_sizes, int n_in,
                              void* d_out, int out_size, void* d_ws, size_t ws_size,
                              hipStream_t stream)
{
    (void)in_sizes; (void)n_in; (void)out_size; (void)ws_size;
    const float* z  = (const float*)d_in[0];
    const float* W1 = (const float*)d_in[1];
    const float* b1 = (const float*)d_in[2];
    const float* W2 = (const float*)d_in[3];
    const float* b2 = (const float*)d_in[4];
    const float* Wm = (const float*)d_in[5];
    const float* bm = (const float*)d_in[6];
    const float* Wv = (const float*)d_in[7];
    const float* bv = (const float*)d_in[8];
    float* out = (float*)d_out;

    const size_t EL = (size_t)BATCH * HID;   // 8,388,608

    // ws layout (~170 MB). lv (113 MB, written in stage 4) hosts the
    // transient zh/zl/h1h/h1l (64 MB, all dead before stage 4).
    float* lv = (float*)d_ws;                                  // 8192*3456 f32
    unsigned short* zh  = (unsigned short*)d_ws;
    unsigned short* zl  = zh  + EL;
    unsigned short* h1h = zl  + EL;
    unsigned short* h1l = h1h + EL;
    unsigned short* hh  = (unsigned short*)(lv + (size_t)BATCH * NLV);
    unsigned short* hl  = hh  + EL;
    unsigned short* W1h = hl  + EL;
    unsigned short* W1l = W1h + (size_t)HID * HID;
    unsigned short* W2h = W1l + (size_t)HID * HID;
    unsigned short* W2l = W2h + (size_t)HID * HID;
    unsigned short* Wmh = W2l + (size_t)HID * HID;
    unsigned short* Wml = Wmh + (size_t)NM * HID;
    unsigned short* Wvh = Wml + (size_t)NM * HID;
    unsigned short* Wvl = Wvh + (size_t)NLV * HID;

    dim3 tb(32, 8);
    conv_blockify<<<dim3(4096), 256, 0, stream>>>(z, zh, zl);
    transpose_split_blk<<<dim3(HID / 32, HID / 32), tb, 0, stream>>>(W1, W1h, W1l, HID);
    transpose_split_blk<<<dim3(HID / 32, HID / 32), tb, 0, stream>>>(W2, W2h, W2l, HID);
    transpose_split_blk<<<dim3(NM  / 32, HID / 32), tb, 0, stream>>>(Wm, Wmh, Wml, NM);
    transpose_split_blk<<<dim3(NLV / 32, HID / 32), tb, 0, stream>>>(Wv, Wvh, Wvl, NLV);

    // h1 = silu(z @ W1 + b1)          -> hi/lo block layout
    gemm_bs<1, 1><<<dim3(BATCH / 128, HID / 128), 256, 0, stream>>>(
        zh, zl, W1h, W1l, b1, nullptr, h1h, h1l, HID);
    // h = h1 @ W2 + b2                -> hi/lo block layout
    gemm_bs<0, 1><<<dim3(BATCH / 128, HID / 128), 256, 0, stream>>>(
        h1h, h1l, W2h, W2l, b2, nullptr, hh, hl, HID);
    // means = h @ Wm + bm             -> d_out (fp32 row-major)
    gemm_bs<0, 0><<<dim3(BATCH / 128, NM / 128), 256, 0, stream>>>(
        hh, hl, Wmh, Wml, bm, out, nullptr, nullptr, NM);
    // lv = h @ Wv + bv                -> ws (fp32 row-major)
    gemm_bs<0, 0><<<dim3(BATCH / 128, NLV / 128), 256, 0, stream>>>(
        hh, hl, Wvh, Wvl, bv, lv, nullptr, nullptr, NLV);

    // precision / D / T
    mcd_epilogue<<<dim3(BATCH * FH / 256), 256, 0, stream>>>(lv, out);
}

// Round 5
// 1168.323 us; speedup vs baseline: 1.0920x; 1.0138x over previous
//
#include <hip/hip_runtime.h>
#include <math.h>

#define BATCH 8192
#define HID   1024
#define FH    96
#define OO    8
#define EE    36
#define NLV   (FH*EE)   // 3456
#define NM    (FH*OO)   // 768

typedef short  bf16x8 __attribute__((ext_vector_type(8)));
typedef float  f32x4  __attribute__((ext_vector_type(4)));
typedef unsigned short u16x8 __attribute__((ext_vector_type(8)));
typedef unsigned short u16x4 __attribute__((ext_vector_type(4)));

// d_out layout (floats): means | precision | D | T
static const size_t OFF_P = (size_t)BATCH * FH * OO;
static const size_t OFF_D = OFF_P + (size_t)BATCH * FH * 64;
static const size_t OFF_T = OFF_D + (size_t)BATCH * FH * 64;

__device__ __forceinline__ unsigned short f2bf(float f) {
    unsigned int u = __float_as_uint(f);
    u += 0x7fffu + ((u >> 16) & 1u);
    return (unsigned short)(u >> 16);
}
__device__ __forceinline__ float bf2f(unsigned short s) {
    return __uint_as_float(((unsigned int)s) << 16);
}

// Block layout for GEMM operands (both A and B sides), K = HID always:
// elem (r, k) -> [r>>7][k>>3][r&127][k&7]; 128-row block stride = 128*HID.
// A 128x32 tile at (rblk, k0) is 4 contiguous 2KB kgrp slabs -> global_load_lds
// staging is linear AND fully coalesced.
__device__ __forceinline__ size_t blk_off(int r, int k) {
    return ((size_t)(r >> 7)) * (128 * HID) + (size_t)(k >> 3) * 1024
         + (size_t)(r & 127) * 8 + (size_t)(k & 7);
}

// async global->LDS, 16B per lane; LDS dest = wave-uniform base + lane*16
__device__ __forceinline__ void glds16(const unsigned short* g, unsigned short* l) {
    __builtin_amdgcn_global_load_lds(
        (const __attribute__((address_space(1))) unsigned int*)g,
        (__attribute__((address_space(3))) unsigned int*)l, 16, 0, 0);
}

// ---------------------------------------------------------------------------
// fp32 [R][HID] row-major -> hi/lo bf16 block layout. Contiguous writes.
__global__ __launch_bounds__(256) void conv_blockify(const float* __restrict__ X,
                                                     unsigned short* __restrict__ Xh,
                                                     unsigned short* __restrict__ Xl)
{
    int idx  = blockIdx.x * 256 + threadIdx.x;   // one 8-elem chunk
    int row  = idx & 127;
    int kgrp = (idx >> 7) & 127;
    int rblk = idx >> 14;
    const float* src = X + ((size_t)(rblk * 128 + row)) * HID + kgrp * 8;
    float4 v0 = reinterpret_cast<const float4*>(src)[0];
    float4 v1 = reinterpret_cast<const float4*>(src)[1];
    float vv[8] = {v0.x, v0.y, v0.z, v0.w, v1.x, v1.y, v1.z, v1.w};
    u16x8 h, l;
#pragma unroll
    for (int j = 0; j < 8; ++j) {
        unsigned short hh = f2bf(vv[j]);
        h[j] = hh;
        l[j] = f2bf(vv[j] - bf2f(hh));
    }
    *reinterpret_cast<u16x8*>(Xh + (size_t)idx * 8) = h;
    *reinterpret_cast<u16x8*>(Xl + (size_t)idx * 8) = l;
}

// ---------------------------------------------------------------------------
// W (fp32 [K=HID][N]) -> hi/lo bf16, transposed into block layout (r = n).
__global__ __launch_bounds__(256) void transpose_split_blk(const float* __restrict__ W,
                                                           unsigned short* __restrict__ Th,
                                                           unsigned short* __restrict__ Tl,
                                                           int N)
{
    __shared__ float sh[32][33];
    const int tx = threadIdx.x;          // 0..31
    const int ty = threadIdx.y;          // 0..7
    const int n0 = blockIdx.x * 32;
    const int k0 = blockIdx.y * 32;
#pragma unroll
    for (int i = 0; i < 4; ++i) {
        int kl = ty + i * 8;
        sh[kl][tx] = W[(size_t)(k0 + kl) * N + n0 + tx];
    }
    __syncthreads();
#pragma unroll
    for (int i = 0; i < 4; ++i) {
        int nl = ty + i * 8;
        float v = sh[tx][nl];            // = W[k0+tx][n0+nl]
        unsigned short h = f2bf(v);
        unsigned short l = f2bf(v - bf2f(h));
        size_t o = blk_off(n0 + nl, k0 + tx);
        Th[o] = h;
        Tl[o] = l;
    }
}

// ---------------------------------------------------------------------------
// Split-bf16 MFMA GEMM, both operands pre-split hi/lo in block layout.
// 3 passes AhBh + AhBl + AlBh. Tile 128x128, BK=32, 4 waves 2x2, per-wave
// 4x4 frags of v_mfma_f32_16x16x32_bf16 with SWAPPED operands:
//   acc = mfma(b_frag, a_frag)  ->  D col(lane&15)=batch row m,
//                                   D row(4*(lane>>4)+reg)=output col n
// so each thread owns 4 CONSECUTIVE output cols -> vector stores.
// 2-phase double-buffered LDS (catalog T3-min): stage(buf^1) issued BEFORE
// ds_read+MFMA of buf; single __syncthreads (vmcnt0 drain) per k-step lands
// after the MFMA block, hiding most of the staging flight.
template<int ACT, int OUTBLK>
__global__ __launch_bounds__(256) void gemm_bs(
    const unsigned short* __restrict__ Ah_, const unsigned short* __restrict__ Al_,
    const unsigned short* __restrict__ Bh_, const unsigned short* __restrict__ Bl_,
    const float* __restrict__ bias,
    float* __restrict__ Cf,
    unsigned short* __restrict__ Ch, unsigned short* __restrict__ Cl,
    int N)
{
    __shared__ unsigned short L[2][4][4096];   // [buf][Ah,Al,Bh,Bl][4 kgrp][128 row][8]

    const int tid  = threadIdx.x;
    const int lane = tid & 63;
    const int wave = tid >> 6;
    const int m0   = blockIdx.x * 128;
    const int n0   = blockIdx.y * 128;
    const int wm0  = (wave >> 1) * 64;
    const int wn0  = (wave & 1) * 64;
    const int l15  = lane & 15;
    const int l4   = lane >> 4;

    const unsigned short* Ah = Ah_ + (size_t)(m0 >> 7) * (128 * HID);
    const unsigned short* Al = Al_ + (size_t)(m0 >> 7) * (128 * HID);
    const unsigned short* Bh = Bh_ + (size_t)(n0 >> 7) * (128 * HID);
    const unsigned short* Bl = Bl_ + (size_t)(n0 >> 7) * (128 * HID);

    f32x4 acc[4][4];
#pragma unroll
    for (int i = 0; i < 4; ++i)
#pragma unroll
        for (int j = 0; j < 4; ++j)
            acc[i][j] = (f32x4){0.f, 0.f, 0.f, 0.f};

    const int c0 = wave * 2;       // each wave stages chunks {c0, c0+1} of each buffer
    const int c1 = c0 + 1;

    auto stage = [&](int buf, int k0) {
        const size_t tb = (size_t)(k0 >> 3) * 1024;   // tile base (elems) in block layout
        const size_t o0 = tb + (size_t)c0 * 512 + (size_t)lane * 8;
        const size_t o1 = tb + (size_t)c1 * 512 + (size_t)lane * 8;
        glds16(Ah + o0, &L[buf][0][c0 * 512]);
        glds16(Ah + o1, &L[buf][0][c1 * 512]);
        glds16(Al + o0, &L[buf][1][c0 * 512]);
        glds16(Al + o1, &L[buf][1][c1 * 512]);
        glds16(Bh + o0, &L[buf][2][c0 * 512]);
        glds16(Bh + o1, &L[buf][2][c1 * 512]);
        glds16(Bl + o0, &L[buf][3][c0 * 512]);
        glds16(Bl + o1, &L[buf][3][c1 * 512]);
    };

    // prologue: stage tile 0, wait for it
    stage(0, 0);
    __syncthreads();

    int buf = 0;
    for (int k0 = 0; k0 < HID; k0 += 32) {
        // issue next tile's staging FIRST (flight overlaps reads + MFMA below)
        if (k0 + 32 < HID) stage(buf ^ 1, k0 + 32);

        // fragments of current tile
        bf16x8 a_h[4], a_l[4];
#pragma unroll
        for (int mf = 0; mf < 4; ++mf) {
            int off = l4 * 1024 + (wm0 + mf * 16 + l15) * 8;
            a_h[mf] = *reinterpret_cast<const bf16x8*>(&L[buf][0][off]);
            a_l[mf] = *reinterpret_cast<const bf16x8*>(&L[buf][1][off]);
        }
#pragma unroll
        for (int nf = 0; nf < 4; ++nf) {
            int off = l4 * 1024 + (wn0 + nf * 16 + l15) * 8;
            bf16x8 b_h = *reinterpret_cast<const bf16x8*>(&L[buf][2][off]);
            bf16x8 b_l = *reinterpret_cast<const bf16x8*>(&L[buf][3][off]);
#pragma unroll
            for (int mf = 0; mf < 4; ++mf) {
                acc[mf][nf] = __builtin_amdgcn_mfma_f32_16x16x32_bf16(b_h, a_h[mf], acc[mf][nf], 0, 0, 0);
                acc[mf][nf] = __builtin_amdgcn_mfma_f32_16x16x32_bf16(b_l, a_h[mf], acc[mf][nf], 0, 0, 0);
                acc[mf][nf] = __builtin_amdgcn_mfma_f32_16x16x32_bf16(b_h, a_l[mf], acc[mf][nf], 0, 0, 0);
            }
        }
        __syncthreads();   // vmcnt(0)+lgkm drain + barrier: next tile resident
        buf ^= 1;
    }

    // ---- epilogue (swapped mapping: thread owns row gm, col quad nq..nq+3) ----
#pragma unroll
    for (int mf = 0; mf < 4; ++mf) {
        int gm = m0 + wm0 + mf * 16 + l15;
#pragma unroll
        for (int nf = 0; nf < 4; ++nf) {
            int nq = wn0 + nf * 16 + l4 * 4;      // block-local col quad base
            float4 bb = *reinterpret_cast<const float4*>(bias + n0 + nq);
            float o[4];
            o[0] = acc[mf][nf][0] + bb.x;
            o[1] = acc[mf][nf][1] + bb.y;
            o[2] = acc[mf][nf][2] + bb.z;
            o[3] = acc[mf][nf][3] + bb.w;
            if (ACT) {
#pragma unroll
                for (int r = 0; r < 4; ++r) o[r] = o[r] / (1.f + __expf(-o[r]));
            }
            if (OUTBLK == 0) {
                *reinterpret_cast<float4*>(Cf + (size_t)gm * N + n0 + nq) =
                    make_float4(o[0], o[1], o[2], o[3]);
            } else {
                u16x4 hv, lv4;
#pragma unroll
                for (int r = 0; r < 4; ++r) {
                    unsigned short hh = f2bf(o[r]);
                    hv[r] = hh;
                    lv4[r] = f2bf(o[r] - bf2f(hh));
                }
                size_t off = blk_off(gm, n0 + nq);   // N == HID for these stages
                *reinterpret_cast<u16x4*>(Ch + off) = hv;
                *reinterpret_cast<u16x4*>(Cl + off) = lv4;
            }
        }
    }
}

// ---------------------------------------------------------------------------
// MCD epilogue: per (row, head) group read 36 log-var values, emit
// precision (T^T D^-1 T), D, T. 1 thread = 1 group; fully thread-local.
__global__ __launch_bounds__(256) void mcd_epilogue(const float* __restrict__ lv,
                                                    float* __restrict__ out)
{
    const int gid  = blockIdx.x * 256 + threadIdx.x;

    const float* src = lv + (size_t)gid * EE;
    float e[EE];
#pragma unroll
    for (int i = 0; i < 9; ++i)
        *reinterpret_cast<float4*>(&e[i * 4]) =
            reinterpret_cast<const float4*>(src)[i];

    float dv[OO], invd[OO];
#pragma unroll
    for (int i = 0; i < OO; ++i) {
        dv[i]   = __expf(0.5f * e[i]);
        invd[i] = 1.f / dv[i];
    }

    float Tu[OO][OO];
#pragma unroll
    for (int j = 0; j < OO; ++j) {
#pragma unroll
        for (int i = j + 1; i < OO; ++i) {
            Tu[j][i] = e[OO + j * 7 - (j * (j - 1)) / 2 + (i - j - 1)];
        }
    }

    float* Pp = out + OFF_P + (size_t)gid * 64;
    float* Dp = out + OFF_D + (size_t)gid * 64;
    float* Tp = out + OFF_T + (size_t)gid * 64;

#pragma unroll
    for (int i = 0; i < OO; ++i) {
        float rowv[OO];
#pragma unroll
        for (int k = 0; k < OO; ++k) {
            float s = 0.f;
#pragma unroll
            for (int j = 0; j < OO; ++j) {
                if (j <= i && j <= k) {
                    float tji = (j == i) ? 1.f : Tu[j][i];
                    float tjk = (j == k) ? 1.f : Tu[j][k];
                    s = fmaf(tji, tjk * invd[j], s);
                }
            }
            rowv[k] = s;
        }
        *reinterpret_cast<float4*>(Pp + i * 8)     = make_float4(rowv[0], rowv[1], rowv[2], rowv[3]);
        *reinterpret_cast<float4*>(Pp + i * 8 + 4) = make_float4(rowv[4], rowv[5], rowv[6], rowv[7]);
    }

#pragma unroll
    for (int i = 0; i < OO; ++i) {
        float rowv[OO];
#pragma unroll
        for (int k = 0; k < OO; ++k) rowv[k] = (k == i) ? dv[i] : 0.f;
        *reinterpret_cast<float4*>(Dp + i * 8)     = make_float4(rowv[0], rowv[1], rowv[2], rowv[3]);
        *reinterpret_cast<float4*>(Dp + i * 8 + 4) = make_float4(rowv[4], rowv[5], rowv[6], rowv[7]);
    }

#pragma unroll
    for (int j = 0; j < OO; ++j) {
        float rowv[OO];
#pragma unroll
        for (int k = 0; k < OO; ++k)
            rowv[k] = (k < j) ? 0.f : (k == j) ? 1.f : Tu[j][k];
        *reinterpret_cast<float4*>(Tp + j * 8)     = make_float4(rowv[0], rowv[1], rowv[2], rowv[3]);
        *reinterpret_cast<float4*>(Tp + j * 8 + 4) = make_float4(rowv[4], rowv[5], rowv[6], rowv[7]);
    }
}

// ---------------------------------------------------------------------------
extern "C" void kernel_launch(void* const* d_in, const int* in_sizes, int n_in,
                              void* d_out, int out_size, void* d_ws, size_t ws_size,
                              hipStream_t stream)
{
    (void)in_sizes; (void)n_in; (void)out_size; (void)ws_size;
    const float* z  = (const float*)d_in[0];
    const float* W1 = (const float*)d_in[1];
    const float* b1 = (const float*)d_in[2];
    const float* W2 = (const float*)d_in[3];
    const float* b2 = (const float*)d_in[4];
    const float* Wm = (const float*)d_in[5];
    const float* bm = (const float*)d_in[6];
    const float* Wv = (const float*)d_in[7];
    const float* bv = (const float*)d_in[8];
    float* out = (float*)d_out;

    const size_t EL = (size_t)BATCH * HID;   // 8,388,608

    // ws layout (~170 MB). lv (113 MB, written in stage 4) hosts the
    // transient zh/zl/h1h/h1l (64 MB, all dead before stage 4).
    float* lv = (float*)d_ws;                                  // 8192*3456 f32
    unsigned short* zh  = (unsigned short*)d_ws;
    unsigned short* zl  = zh  + EL;
    unsigned short* h1h = zl  + EL;
    unsigned short* h1l = h1h + EL;
    unsigned short* hh  = (unsigned short*)(lv + (size_t)BATCH * NLV);
    unsigned short* hl  = hh  + EL;
    unsigned short* W1h = hl  + EL;
    unsigned short* W1l = W1h + (size_t)HID * HID;
    unsigned short* W2h = W1l + (size_t)HID * HID;
    unsigned short* W2l = W2h + (size_t)HID * HID;
    unsigned short* Wmh = W2l + (size_t)HID * HID;
    unsigned short* Wml = Wmh + (size_t)NM * HID;
    unsigned short* Wvh = Wml + (size_t)NM * HID;
    unsigned short* Wvl = Wvh + (size_t)NLV * HID;

    dim3 tb(32, 8);
    conv_blockify<<<dim3(4096), 256, 0, stream>>>(z, zh, zl);
    transpose_split_blk<<<dim3(HID / 32, HID / 32), tb, 0, stream>>>(W1, W1h, W1l, HID);
    transpose_split_blk<<<dim3(HID / 32, HID / 32), tb, 0, stream>>>(W2, W2h, W2l, HID);
    transpose_split_blk<<<dim3(NM  / 32, HID / 32), tb, 0, stream>>>(Wm, Wmh, Wml, NM);
    transpose_split_blk<<<dim3(NLV / 32, HID / 32), tb, 0, stream>>>(Wv, Wvh, Wvl, NLV);

    // h1 = silu(z @ W1 + b1)          -> hi/lo block layout
    gemm_bs<1, 1><<<dim3(BATCH / 128, HID / 128), 256, 0, stream>>>(
        zh, zl, W1h, W1l, b1, nullptr, h1h, h1l, HID);
    // h = h1 @ W2 + b2                -> hi/lo block layout
    gemm_bs<0, 1><<<dim3(BATCH / 128, HID / 128), 256, 0, stream>>>(
        h1h, h1l, W2h, W2l, b2, nullptr, hh, hl, HID);
    // means = h @ Wm + bm             -> d_out (fp32 row-major)
    gemm_bs<0, 0><<<dim3(BATCH / 128, NM / 128), 256, 0, stream>>>(
        hh, hl, Wmh, Wml, bm, out, nullptr, nullptr, NM);
    // lv = h @ Wv + bv                -> ws (fp32 row-major)
    gemm_bs<0, 0><<<dim3(BATCH / 128, NLV / 128), 256, 0, stream>>>(
        hh, hl, Wvh, Wvl, bv, lv, nullptr, nullptr, NLV);

    // precision / D / T
    mcd_epilogue<<<dim3(BATCH * FH / 256), 256, 0, stream>>>(lv, out);
}